// Round 7
// baseline (945.709 us; speedup 1.0000x reference)
//
#include <hip/hip_runtime.h>
#include <hip/hip_bf16.h>

typedef __hip_bfloat16 bf16;
typedef __attribute__((ext_vector_type(8))) short short8;
typedef __attribute__((ext_vector_type(4))) float float4v;

#define B_    64
#define CH_   512
#define TD_   256
#define H_    4
#define DH_   64
#define TLAT  1000
#define TTXT  512
#define SCALE_ 0.0625f

__device__ __forceinline__ float cvt(float x) { return x; }
__device__ __forceinline__ float cvt(bf16 x)  { return __bfloat162float(x); }
__device__ __forceinline__ void stv(float* p, float v) { *p = v; }
__device__ __forceinline__ void stv(bf16* p, float v)  { *p = __float2bfloat16(v); }

__device__ __forceinline__ unsigned short f2bu(float f) {
  bf16 h = __float2bfloat16(f);
  unsigned short u; __builtin_memcpy(&u, &h, 2); return u;
}
__device__ __forceinline__ float bu2f(unsigned short u) {
  bf16 h; __builtin_memcpy(&h, &u, 2); return __bfloat162float(h);
}

// LDS XOR swizzle (T2/G4): element (row,col) -> col ^ ((row&7)<<3), ushort
// units. Flips 16B-chunk index bits only, preserves 16B alignment.
__device__ __forceinline__ int swz(int row, int col) {
  return col ^ ((row & 7) << 3);
}

// Vector load/store helpers (4 elems), dtype-polymorphic.
__device__ __forceinline__ float4 ld4(const float* p) { return *(const float4*)p; }
__device__ __forceinline__ float4 ld4(const bf16* p) {
  ushort4 u = *(const ushort4*)p;
  return make_float4(bu2f(u.x), bu2f(u.y), bu2f(u.z), bu2f(u.w));
}
__device__ __forceinline__ void st4(float* p, float4 v) { *(float4*)p = v; }
__device__ __forceinline__ void st4(bf16* p, float4 v) {
  ushort4 u = make_ushort4(f2bu(v.x), f2bu(v.y), f2bu(v.z), f2bu(v.w));
  *(ushort4*)p = u;
}

// ---------------------------------------------------------------------------
// dtype probe: increments = arange(1000). fp32 words 1..3 == 1,2,3 iff fp32.
// ---------------------------------------------------------------------------
__global__ void detect_k(const void* inc, int* flag) {
  const float* f = (const float*)inc;
  float err = fabsf(f[1] - 1.f) + fabsf(f[2] - 2.f) + fabsf(f[3] - 3.f);
  *flag = (err < 0.5f) ? 0 : 1;   // 0 = fp32, 1 = bf16
}

// ---------------------------------------------------------------------------
// Weight convert: Wq(256x512), Wk(256x256), Wv(256x256), Wo(512x256) -> bf16.
// ---------------------------------------------------------------------------
template<typename T>
__device__ __forceinline__ void cvtw_body(const void* a, const void* b2,
                                          const void* c, const void* d,
                                          unsigned short* out) {
  int i = blockIdx.x * 256 + threadIdx.x;   // total 393216
  float v;
  if (i < 131072)      v = cvt(((const T*)a)[i]);
  else if (i < 196608) v = cvt(((const T*)b2)[i - 131072]);
  else if (i < 262144) v = cvt(((const T*)c)[i - 196608]);
  else                 v = cvt(((const T*)d)[i - 262144]);
  out[i] = f2bu(v);
}

__global__ __launch_bounds__(256) void cvtw_k(
    const int* __restrict__ flag, const void* a, const void* b2,
    const void* c, const void* d, unsigned short* out) {
  if (*flag) cvtw_body<bf16>(a, b2, c, d, out);
  else       cvtw_body<float>(a, b2, c, d, out);
}

// ---------------------------------------------------------------------------
// Transpose + convert: in T [b][K][M] (k-major) -> out bf16 [b][M][K].
// ---------------------------------------------------------------------------
template<typename T>
__device__ __forceinline__ void transpose_body(
    const void* inv, size_t ioff, size_t strideIn,
    unsigned short* out, size_t strideOut, int K, int M,
    unsigned int (*Ls)[33]) {
  const T* in = (const T*)inv + ioff + (size_t)blockIdx.z * strideIn;
  unsigned short* ob = out + (size_t)blockIdx.z * strideOut;
  const int m0 = blockIdx.x * 64, k0 = blockIdx.y * 64;
  const int tid = threadIdx.x;
  const int ml = tid & 63;
  int mrd = m0 + ml; if (mrd >= M) mrd = M - 1;
#pragma unroll
  for (int it = 0; it < 8; it++) {
    int kp = it * 4 + (tid >> 6);          // 0..31 (k-pair index)
    int k = k0 + kp * 2;
    float v0 = cvt(in[(size_t)k * M + mrd]);
    float v1 = cvt(in[(size_t)(k + 1) * M + mrd]);
    Ls[ml][kp] = (unsigned)f2bu(v0) | ((unsigned)f2bu(v1) << 16);
  }
  __syncthreads();
#pragma unroll
  for (int it = 0; it < 8; it++) {
    int idx = it * 256 + tid;
    int my = idx >> 5, kk = idx & 31;
    int m = m0 + my;
    if (m < M)
      *(unsigned*)&ob[(size_t)m * K + k0 + kk * 2] = Ls[my][kk];
  }
}

__global__ __launch_bounds__(256) void transpose_k(
    const int* __restrict__ flag, const void* in, size_t ioff, size_t strideIn,
    unsigned short* out, size_t strideOut, int K, int M) {
  __shared__ unsigned int Ls[64][33];
  if (*flag) transpose_body<bf16>(in, ioff, strideIn, out, strideOut, K, M, Ls);
  else       transpose_body<float>(in, ioff, strideIn, out, strideOut, K, M, Ls);
}

// ---------------------------------------------------------------------------
// MFMA GEMM core: D[m][n] = sum_k A[m][k] * B[n][k], bf16 in, fp32 accum.
// 128x128 tile, BK=32, 4 waves 2x2, 4x4 16x16x32 frags per wave.
// Register software-prefetch: iter k+1's global loads are issued before
// iter k's ds_read+MFMA so the vmcnt drain at the barrier finds them aged.
// ---------------------------------------------------------------------------
__device__ __forceinline__ void gemm_core(
    const unsigned short* __restrict__ Ab, int lda, int M,
    const unsigned short* __restrict__ Bb, int ldb, int N, int K,
    int m0, int n0,
    unsigned short (*As)[40], unsigned short (*Bs)[40],
    float4v (&acc)[4][4]) {
  const int tid = threadIdx.x;
  const int lane = tid & 63, w = tid >> 6;
  const int lq = lane & 15, quad = lane >> 4;
  const int wm = (w >> 1) * 64, wn = (w & 1) * 64;
  const int srow = tid >> 2;
  const int sch  = (tid & 3) * 8;

  int ra[2], rb[2];
#pragma unroll
  for (int hf = 0; hf < 2; hf++) {
    int r0 = m0 + hf * 64 + srow; ra[hf] = (r0 < M) ? r0 : (M - 1);
    int r1 = n0 + hf * 64 + srow; rb[hf] = (r1 < N) ? r1 : (N - 1);
  }

#pragma unroll
  for (int i = 0; i < 4; i++)
#pragma unroll
    for (int j = 0; j < 4; j++) acc[i][j] = (float4v){0.f, 0.f, 0.f, 0.f};

  uint4 va[2], vb[2];
#pragma unroll
  for (int hf = 0; hf < 2; hf++) {
    va[hf] = *(const uint4*)(Ab + (size_t)ra[hf] * lda + sch);
    vb[hf] = *(const uint4*)(Bb + (size_t)rb[hf] * ldb + sch);
  }

  for (int k0 = 0; k0 < K; k0 += 32) {
    __syncthreads();                       // prev iter done reading LDS
#pragma unroll
    for (int hf = 0; hf < 2; hf++) {
      *(uint4*)&As[hf * 64 + srow][sch] = va[hf];
      *(uint4*)&Bs[hf * 64 + srow][sch] = vb[hf];
    }
    __syncthreads();

    uint4 na[2] = {va[0], va[1]}, nb[2] = {vb[0], vb[1]};
    if (k0 + 32 < K) {
#pragma unroll
      for (int hf = 0; hf < 2; hf++) {
        na[hf] = *(const uint4*)(Ab + (size_t)ra[hf] * lda + k0 + 32 + sch);
        nb[hf] = *(const uint4*)(Bb + (size_t)rb[hf] * ldb + k0 + 32 + sch);
      }
    }

    short8 af[4], bfr[4];
#pragma unroll
    for (int i = 0; i < 4; i++) {
      af[i]  = *(const short8*)&As[wm + i * 16 + lq][quad * 8];
      bfr[i] = *(const short8*)&Bs[wn + i * 16 + lq][quad * 8];
    }
#pragma unroll
    for (int i = 0; i < 4; i++)
#pragma unroll
      for (int j = 0; j < 4; j++)
        acc[i][j] = __builtin_amdgcn_mfma_f32_16x16x32_bf16(af[i], bfr[j], acc[i][j], 0, 0, 0);

    va[0] = na[0]; va[1] = na[1]; vb[0] = nb[0]; vb[1] = nb[1];
  }
}

// ---------------------------------------------------------------------------
// Epilogue A (coalesced): bf16 C = acc + bias, optional fused RoPE.
// Stage 32x128 chunks in LDS ([32][136] ushort), then store full-line rows.
// RoPE (ropeT > 0, biasByM==0 callers only): output cols n0+wn..n0+wn+63 are
// exactly one head (n0,wn multiples of 64); thread holds pair (d, d+32) as
// (acc[i][jlo], acc[i][jlo+2]), jj = jlo*16+lq, t = m. Rotation in fp32
// before bf16 rounding. ang = inc[t]*inv_seq*theta[jj].
// ---------------------------------------------------------------------------
template<typename T>
__device__ __forceinline__ void epi_store(
    float4v (&acc)[4][4], int m0, int n0, unsigned short* Cb, int ldc, int M, int N,
    const void* biasv, int biasByM, unsigned short* scr,
    const void* incv, const void* thetav, float inv_seq, int ropeT) {
  const T* bias = (const T*)biasv;
  const T* inc_ = (const T*)incv;
  const T* theta_ = (const T*)thetav;
  const int tid = threadIdx.x;
  const int lane = tid & 63, w = tid >> 6;
  const int lq = lane & 15, quad = lane >> 4;
  const int wm = (w >> 1) * 64, wn = (w & 1) * 64;
  const int rbase = (w >> 1) * 16 + quad * 4;
  const int lr = tid >> 3, ck = tid & 7;
  const int mbase = m0 + (lr >> 4) * 64 + (lr & 15);
#pragma unroll
  for (int i = 0; i < 4; i++) {
    __syncthreads();   // prior chunk (or gemm LDS reads) done
    if (ropeT > 0) {
#pragma unroll
      for (int jlo = 0; jlo < 2; jlo++) {
        float b1 = cvt(bias[n0 + wn + jlo * 16 + lq]);
        float b2 = cvt(bias[n0 + wn + (jlo + 2) * 16 + lq]);
        float th = cvt(theta_[jlo * 16 + lq]);
#pragma unroll
        for (int r = 0; r < 4; r++) {
          int t = m0 + wm + i * 16 + quad * 4 + r;
          int tt = (t < ropeT) ? t : (ropeT - 1);
          float ang = cvt(inc_[tt]) * inv_seq * th;
          float s, c;
          __sincosf(ang, &s, &c);
          float v1 = acc[i][jlo][r] + b1;
          float v2 = acc[i][jlo + 2][r] + b2;
          scr[(rbase + r) * 136 + wn + jlo * 16 + lq]       = f2bu(v1 * c - v2 * s);
          scr[(rbase + r) * 136 + wn + (jlo + 2) * 16 + lq] = f2bu(v1 * s + v2 * c);
        }
      }
    } else {
#pragma unroll
      for (int j = 0; j < 4; j++) {
        float bn_ = biasByM ? 0.f : cvt(bias[n0 + wn + j * 16 + lq]);
#pragma unroll
        for (int r = 0; r < 4; r++) {
          float bb = biasByM ? cvt(bias[m0 + wm + i * 16 + quad * 4 + r]) : bn_;
          scr[(rbase + r) * 136 + wn + j * 16 + lq] = f2bu(acc[i][j][r] + bb);
        }
      }
    }
    __syncthreads();
    int m = mbase + i * 16;
    if (m < M) {
#pragma unroll
      for (int u = 0; u < 2; u++) {
        int c = u * 64 + ck * 8;
        *(uint4*)&Cb[(size_t)m * ldc + n0 + c] = *(const uint4*)&scr[lr * 136 + c];
      }
    }
  }
}

__global__ __launch_bounds__(256) void gemm_bf(
    const int* __restrict__ flag,
    const unsigned short* __restrict__ A, size_t strideA, int lda, int M,
    const unsigned short* __restrict__ B, size_t strideB, int ldb, int N, int K,
    unsigned short* C, size_t strideC, int ldc,
    const void* bias, int biasByM,
    const void* inc, const void* theta, float inv_seq, int ropeT) {
  __shared__ __align__(16) unsigned char smem[20480];
  unsigned short (*As)[40] = (unsigned short (*)[40])smem;
  unsigned short (*Bs)[40] = (unsigned short (*)[40])(smem + 10240);
  const int bz = blockIdx.z;
  const int m0 = blockIdx.x * 128, n0 = blockIdx.y * 128;
  float4v acc[4][4];
  gemm_core(A + (size_t)bz * strideA, lda, M,
            B + (size_t)bz * strideB, ldb, N, K, m0, n0, As, Bs, acc);
  unsigned short* Cb = C + (size_t)bz * strideC;
  unsigned short* scr = (unsigned short*)smem;   // 32*136*2 = 8704 B
  if (*flag) epi_store<bf16>(acc, m0, n0, Cb, ldc, M, N, bias, biasByM, scr, inc, theta, inv_seq, ropeT);
  else       epi_store<float>(acc, m0, n0, Cb, ldc, M, N, bias, biasByM, scr, inc, theta, inv_seq, ropeT);
}

// ---------------------------------------------------------------------------
// Epilogue B: output projection. m = channel c (M=512), n = t (N=1000).
// Out[b][c][t] = (acc + bo[c] + x[b][c][t]) * lmask[b][t].
// Half-wave writes 512 B contiguous of one row. MLP: lmask hoisted (depends
// only on n), X prefetched one i-chunk ahead so loads age across the barrier.
// ---------------------------------------------------------------------------
template<typename T>
__device__ __forceinline__ void epi_out(
    float4v (&acc)[4][4], int m0, int n0, int bz, int M, int N,
    const void* biasv, const void* Xv, size_t xoffE,
    const void* lmv, size_t lmoffE, void* Outv, size_t ooffE, size_t strideO,
    float* scr) {
  const T* bias = (const T*)biasv;
  const T* X  = (const T*)Xv + xoffE;
  const T* lm = (const T*)lmv + lmoffE;
  T* Out      = (T*)Outv + ooffE;
  const int tid = threadIdx.x;
  const int lane = tid & 63, w = tid >> 6;
  const int lq = lane & 15, quad = lane >> 4;
  const int wm = (w >> 1) * 64, wn = (w & 1) * 64;
  const int rbase = (w >> 1) * 16 + quad * 4;
  const int col = (lane & 31) * 4;          // 0..124
  const int rw  = w * 2 + (lane >> 5);      // 0..7
  const int n = n0 + col;
  const bool nok = (n < N);
  float4 vl = make_float4(0.f, 0.f, 0.f, 0.f);
  if (nok) vl = ld4(lm + (size_t)bz * TLAT + n);

  float4 px[4];
#pragma unroll
  for (int p = 0; p < 4; p++) {
    int lr2 = p * 8 + rw;
    int m = m0 + (lr2 >> 4) * 64 + (lr2 & 15);
    px[p] = (m < M && nok) ? ld4(X + (size_t)bz * strideO + (size_t)m * TLAT + n)
                           : make_float4(0.f, 0.f, 0.f, 0.f);
  }
#pragma unroll
  for (int i = 0; i < 4; i++) {
    __syncthreads();
#pragma unroll
    for (int j = 0; j < 4; j++)
#pragma unroll
      for (int r = 0; r < 4; r++) {
        int m = m0 + wm + i * 16 + quad * 4 + r;
        scr[(rbase + r) * 136 + wn + j * 16 + lq] = acc[i][j][r] + cvt(bias[m]);
      }
    __syncthreads();
    float4 nx[4];
#pragma unroll
    for (int p = 0; p < 4; p++) nx[p] = px[p];
    if (i < 3) {
#pragma unroll
      for (int p = 0; p < 4; p++) {
        int lr2 = p * 8 + rw;
        int m = m0 + (lr2 >> 4) * 64 + (lr2 & 15) + (i + 1) * 16;
        nx[p] = (m < M && nok) ? ld4(X + (size_t)bz * strideO + (size_t)m * TLAT + n)
                               : make_float4(0.f, 0.f, 0.f, 0.f);
      }
    }
#pragma unroll
    for (int p = 0; p < 4; p++) {
      int lr2 = p * 8 + rw;
      int m = m0 + (lr2 >> 4) * 64 + (lr2 & 15) + i * 16;
      if (m < M && nok) {
        size_t rowo = (size_t)bz * strideO + (size_t)m * TLAT;
        float4 sv = *(const float4*)&scr[lr2 * 136 + col];
        float4 v;
        v.x = (sv.x + px[p].x) * vl.x;
        v.y = (sv.y + px[p].y) * vl.y;
        v.z = (sv.z + px[p].z) * vl.z;
        v.w = (sv.w + px[p].w) * vl.w;
        st4(Out + rowo + n, v);
      }
    }
#pragma unroll
    for (int p = 0; p < 4; p++) px[p] = nx[p];
  }
}

__global__ __launch_bounds__(256) void gemm_bf_out(
    const int* __restrict__ flag,
    const unsigned short* __restrict__ A, size_t strideA, int lda, int M,
    const unsigned short* __restrict__ B, size_t strideB, int ldb, int N, int K,
    const void* bias, const void* X, size_t xoffE,
    const void* lmask, size_t lmoffE, void* Out, size_t ooffE, size_t strideO) {
  __shared__ __align__(16) unsigned char smem[20480];
  unsigned short (*As)[40] = (unsigned short (*)[40])smem;
  unsigned short (*Bs)[40] = (unsigned short (*)[40])(smem + 10240);

  // XCD swizzle (bijective, guarded on exact grid 4x8x64): one XCD gets all
  // 8 t-tiles of a (channel-tile, batch) so boundary lines merge in one L2.
  int bx = blockIdx.x, by = blockIdx.y, bz = blockIdx.z;
  if (gridDim.x == 4 && gridDim.y == 8 && gridDim.z == 64) {
    int lin = blockIdx.x + (blockIdx.y << 2) + (blockIdx.z << 5);
    int k = lin & 7, j = lin >> 3;
    by = j & 7; bx = (j >> 3) & 3; bz = (j >> 5) | (k << 3);
  }
  const int m0 = bx * 128, n0 = by * 128;

  float4v acc[4][4];
  gemm_core(A + (size_t)bz * strideA, lda, M,
            B + (size_t)bz * strideB, ldb, N, K, m0, n0, As, Bs, acc);
  float* scr = (float*)smem;                     // 32*136*4 = 17408 B
  if (*flag) epi_out<bf16>(acc, m0, n0, bz, M, N, bias, X, xoffE, lmask, lmoffE, Out, ooffE, strideO, scr);
  else       epi_out<float>(acc, m0, n0, bz, M, N, bias, X, xoffE, lmask, lmoffE, Out, ooffE, strideO, scr);
}

// ---------------------------------------------------------------------------
// MFMA flash attention. Block = (q-tile 64, h, b), 256 thr = 4 waves, each
// wave owns 16 q rows. Keys in 4 tiles of 128.
//   - Q fragments loaded straight from global into regs (no Qs tile).
//   - Ks/Vs/Ps XOR-swizzled (swz) so b128 frag reads hit all 32 banks.
// ---------------------------------------------------------------------------
__global__ __launch_bounds__(256) void attn_mfma(
    const unsigned short* __restrict__ Q, const unsigned short* __restrict__ K,
    const unsigned short* __restrict__ Vt, const int* __restrict__ tmask,
    unsigned short* __restrict__ AO) {
  const int b = blockIdx.z, h = blockIdx.y, q0 = blockIdx.x * 64;
  __shared__ unsigned short Ks[128][64];
  __shared__ unsigned short Vs[64][128];
  __shared__ unsigned short Ps[4][16][128];
  __shared__ float maskf[TTXT];

  const int tid = threadIdx.x;
  const int w = tid >> 6, lane = tid & 63;
  const int lq = lane & 15, quad = lane >> 4;

  // ---- Q frags straight from global (one-time, full 64B lines per quad) ----
  short8 qa0 = (short8){0, 0, 0, 0, 0, 0, 0, 0};
  short8 qa1 = (short8){0, 0, 0, 0, 0, 0, 0, 0};
  {
    int qrow = q0 + w * 16 + lq;
    if (qrow < TLAT) {
      const unsigned short* qp = Q + ((size_t)(b * TLAT + qrow) * TD_ + h * 64);
      qa0 = *(const short8*)(qp + quad * 8);
      qa1 = *(const short8*)(qp + 32 + quad * 8);
    }
  }
  maskf[tid]       = (float)tmask[b * TTXT + tid];
  maskf[tid + 256] = (float)tmask[b * TTXT + 256 + tid];

  float m_old[4] = {-1e30f, -1e30f, -1e30f, -1e30f};
  float l[4] = {0.f, 0.f, 0.f, 0.f};
  float4v Oacc[4];
#pragma unroll
  for (int i = 0; i < 4; i++) Oacc[i] = (float4v){0.f, 0.f, 0.f, 0.f};

  for (int kt = 0; kt < 4; kt++) {
    __syncthreads();                       // prior iter done reading Ks/Vs
#pragma unroll
    for (int it = 0; it < 4; it++) {       // K tile: 128 keys x 64 d
      int c = it * 256 + tid;
      int row = c >> 3, col = (c & 7) * 8;
      *(uint4*)&Ks[row][swz(row, col)] =
        *(const uint4*)(K + ((size_t)(b * TTXT + kt * 128 + row) * TD_ + h * 64 + col));
    }
#pragma unroll
    for (int it = 0; it < 4; it++) {       // V^T tile: 64 d x 128 keys
      int c = it * 256 + tid;
      int row = c >> 4, col = (c & 15) * 8;
      *(uint4*)&Vs[row][swz(row, col)] =
        *(const uint4*)(Vt + (((size_t)b * TD_ + h * 64 + row) * TTXT + kt * 128 + col));
    }
    __syncthreads();

    // ---- S = Q K^T for this wave's 16 rows x 128 keys ----
    float4v Sacc[8];
#pragma unroll
    for (int nt = 0; nt < 8; nt++) {
      int krow = nt * 16 + lq;
      short8 kb0 = *(const short8*)&Ks[krow][swz(krow, quad * 8)];
      short8 kb1 = *(const short8*)&Ks[krow][swz(krow, 32 + quad * 8)];
      float4v s = (float4v){0.f, 0.f, 0.f, 0.f};
      s = __builtin_amdgcn_mfma_f32_16x16x32_bf16(qa0, kb0, s, 0, 0, 0);
      s = __builtin_amdgcn_mfma_f32_16x16x32_bf16(qa1, kb1, s, 0, 0, 0);
      Sacc[nt] = s;
    }
    float mk[8];
#pragma unroll
    for (int nt = 0; nt < 8; nt++) mk[nt] = maskf[kt * 128 + nt * 16 + lq];

    // scale + mask (masked -> -1e30 so it can't raise the max)
#pragma unroll
    for (int nt = 0; nt < 8; nt++)
#pragma unroll
      for (int r = 0; r < 4; r++) {
        float sv = Sacc[nt][r] * SCALE_;
        Sacc[nt][r] = (mk[nt] != 0.f) ? sv : -1e30f;
      }

#pragma unroll
    for (int r = 0; r < 4; r++) {
      float mx = -1e30f;
#pragma unroll
      for (int nt = 0; nt < 8; nt++) mx = fmaxf(mx, Sacc[nt][r]);
      mx = fmaxf(mx, __shfl_xor(mx, 1));
      mx = fmaxf(mx, __shfl_xor(mx, 2));
      mx = fmaxf(mx, __shfl_xor(mx, 4));
      mx = fmaxf(mx, __shfl_xor(mx, 8));
      float mnew = fmaxf(m_old[r], mx);
      float alpha = __expf(m_old[r] - mnew);
      float ps = 0.f;
      int prow = quad * 4 + r;
#pragma unroll
      for (int nt = 0; nt < 8; nt++) {
        float p = (mk[nt] != 0.f) ? __expf(Sacc[nt][r] - mnew) : 0.f;
        ps += p;
        Ps[w][prow][swz(prow, nt * 16 + lq)] = f2bu(p);
      }
      ps += __shfl_xor(ps, 1);
      ps += __shfl_xor(ps, 2);
      ps += __shfl_xor(ps, 4);
      ps += __shfl_xor(ps, 8);
      l[r] = alpha * l[r] + ps;
      m_old[r] = mnew;
#pragma unroll
      for (int dt = 0; dt < 4; dt++) Oacc[dt][r] *= alpha;
    }

    // ---- O += P V (P from per-wave LDS; same-wave RAW, no barrier) ----
#pragma unroll
    for (int dt = 0; dt < 4; dt++) {
#pragma unroll
      for (int ks = 0; ks < 4; ks++) {
        short8 pa = *(const short8*)&Ps[w][lq][swz(lq, ks * 32 + quad * 8)];
        int vrow = dt * 16 + lq;
        short8 vb = *(const short8*)&Vs[vrow][swz(vrow, ks * 32 + quad * 8)];
        Oacc[dt] = __builtin_amdgcn_mfma_f32_16x16x32_bf16(pa, vb, Oacc[dt], 0, 0, 0);
      }
    }
  }

  // ---- normalize + store ----
#pragma unroll
  for (int r = 0; r < 4; r++) {
    int q = q0 + w * 16 + quad * 4 + r;
    if (q < TLAT) {
      float linv = 1.0f / fmaxf(l[r], 1e-30f);
#pragma unroll
      for (int dt = 0; dt < 4; dt++) {
        int d = h * 64 + dt * 16 + lq;
        AO[(size_t)(b * TLAT + q) * TD_ + d] = f2bu(Oacc[dt][r] * linv);
      }
    }
  }
}

extern "C" void kernel_launch(void* const* d_in, const int* in_sizes, int n_in,
                              void* d_out, int out_size, void* d_ws, size_t ws_size,
                              hipStream_t stream) {
  const void* x        = d_in[0];
  const void* text_emb = d_in[1];
  const void* lmask    = d_in[2];
  const int*  tmask    = (const int*)d_in[3];
  const void* Wq = d_in[4];
  const void* bq = d_in[5];
  const void* Wk = d_in[6];
  const void* bk = d_in[7];
  const void* Wv = d_in[8];
  const void* bv = d_in[9];
  const void* Wo = d_in[10];
  const void* bo = d_in[11];
  const void* theta = d_in[12];
  const void* inc   = d_in[13];

  int* dflag = (int*)d_ws;
  unsigned short* wbuf = (unsigned short*)((char*)d_ws + 256);  // 393216 elems
  unsigned short* scratch = wbuf + 393216;
  size_t used = 256 + (size_t)393216 * 2;
  size_t avail = (ws_size > used) ? ws_size - used : 0;

  // Per-batch bf16 scratch: xT(1000*512) + embT(512*256) + q(1000*256)
  //                       + k(512*256) + vT(256*512) + ao(1000*256)
  const size_t per_b_elems = 512000 + 131072 + 256000 + 131072 + 131072 + 256000;
  const size_t per_b_bytes = per_b_elems * 2;                   // ~2.84 MB
  int Bc = (int)(avail / per_b_bytes);
  if (Bc > B_) Bc = B_;
  if (Bc < 1) Bc = 1;

  unsigned short* xT   = scratch;
  unsigned short* embT = xT   + (size_t)Bc * 512000;
  unsigned short* qb   = embT + (size_t)Bc * 131072;
  unsigned short* kb   = qb   + (size_t)Bc * 256000;
  unsigned short* vtb  = kb   + (size_t)Bc * 131072;
  unsigned short* aob  = vtb  + (size_t)Bc * 131072;

  detect_k<<<1, 1, 0, stream>>>(inc, dflag);
  cvtw_k<<<1536, 256, 0, stream>>>(dflag, Wq, Wk, Wv, Wo, wbuf);
  const unsigned short* Wqb = wbuf;
  const unsigned short* Wkb = wbuf + 131072;
  const unsigned short* Wvb = wbuf + 196608;
  const unsigned short* Wob = wbuf + 262144;

  for (int b0 = 0; b0 < B_; b0 += Bc) {
    int bn = B_ - b0; if (bn > Bc) bn = Bc;
    size_t xoffE = (size_t)b0 * CH_ * TLAT;       // fp-elem offset into x
    size_t eoffE = (size_t)b0 * TD_ * TTXT;       // fp-elem offset into text_emb

    // x[b][512][1000] -> xT[b][1000][512] bf16 ; emb[b][256][512] -> embT[b][512][256]
    transpose_k<<<dim3(16, 8, bn), 256, 0, stream>>>(dflag, x, xoffE, 512000,
                                                     xT, 512000, CH_, TLAT);
    transpose_k<<<dim3(8, 4, bn), 256, 0, stream>>>(dflag, text_emb, eoffE, 131072,
                                                    embT, 131072, TD_, TTXT);

    // q[t][d] = xT[t][c] . Wq[d][c] + bq[d], RoPE fused (T=1000)
    gemm_bf<<<dim3(8, 2, bn), 256, 0, stream>>>(dflag, xT, 512000, 512, TLAT,
                                                Wqb, 0, 512, TD_, CH_,
                                                qb, 256000, TD_, bq, 0,
                                                inc, theta, 1.0f / TLAT, TLAT);
    // k[t][d] = embT[t][d'] . Wk[d][d'] + bk[d], RoPE fused (T=512)
    gemm_bf<<<dim3(4, 2, bn), 256, 0, stream>>>(dflag, embT, 131072, 256, TTXT,
                                                Wkb, 0, 256, TD_, TD_,
                                                kb, 131072, TD_, bk, 0,
                                                inc, theta, 1.0f / TTXT, TTXT);
    // vT[d][t] = Wv[d][d'] . embT[t][d'] + bv[d]   (bias by m, no rope)
    gemm_bf<<<dim3(2, 4, bn), 256, 0, stream>>>(dflag, Wvb, 0, 256, TD_,
                                                embT, 131072, 256, TTXT, TD_,
                                                vtb, 131072, TTXT, bv, 1,
                                                inc, theta, 0.f, 0);

    attn_mfma<<<dim3(16, H_, bn), 256, 0, stream>>>(qb, kb, vtb,
                                                    tmask + (size_t)b0 * TTXT, aob);

    // Out[c][t] = (Wo[c][d] . ao[t][d] + bo[c] + x[c][t]) * lmask[t]
    gemm_bf_out<<<dim3(4, 8, bn), 256, 0, stream>>>(dflag, Wob, 0, 256, CH_,
                                                    aob, 256000, 256, TLAT, TD_,
                                                    bo, x, xoffE,
                                                    lmask, (size_t)b0 * TLAT,
                                                    d_out, xoffE, (size_t)CH_ * TLAT);
  }
}

// Round 8
// 682.646 us; speedup vs baseline: 1.3854x; 1.3854x over previous
//
#include <hip/hip_runtime.h>
#include <hip/hip_bf16.h>

typedef __hip_bfloat16 bf16;
typedef __attribute__((ext_vector_type(8))) short short8;
typedef __attribute__((ext_vector_type(4))) float float4v;

#define B_    64
#define CH_   512
#define TD_   256
#define H_    4
#define DH_   64
#define TLAT  1000
#define TTXT  512
#define SCALE_ 0.0625f

__device__ __forceinline__ float cvt(float x) { return x; }
__device__ __forceinline__ float cvt(bf16 x)  { return __bfloat162float(x); }
__device__ __forceinline__ void stv(float* p, float v) { *p = v; }
__device__ __forceinline__ void stv(bf16* p, float v)  { *p = __float2bfloat16(v); }

__device__ __forceinline__ unsigned short f2bu(float f) {
  bf16 h = __float2bfloat16(f);
  unsigned short u; __builtin_memcpy(&u, &h, 2); return u;
}
__device__ __forceinline__ float bu2f(unsigned short u) {
  bf16 h; __builtin_memcpy(&h, &u, 2); return __bfloat162float(h);
}

// LDS XOR swizzle (T2/G4): element (row,col) -> col ^ ((row&7)<<3), ushort
// units. Flips 16B-chunk index bits only, preserves 16B alignment.
__device__ __forceinline__ int swz(int row, int col) {
  return col ^ ((row & 7) << 3);
}

// Vector load/store helpers (4 elems), dtype-polymorphic.
__device__ __forceinline__ float4 ld4(const float* p) { return *(const float4*)p; }
__device__ __forceinline__ float4 ld4(const bf16* p) {
  ushort4 u = *(const ushort4*)p;
  return make_float4(bu2f(u.x), bu2f(u.y), bu2f(u.z), bu2f(u.w));
}
__device__ __forceinline__ void st4(float* p, float4 v) { *(float4*)p = v; }
__device__ __forceinline__ void st4(bf16* p, float4 v) {
  ushort4 u = make_ushort4(f2bu(v.x), f2bu(v.y), f2bu(v.z), f2bu(v.w));
  *(ushort4*)p = u;
}

// ---------------------------------------------------------------------------
// dtype probe: increments = arange(1000). fp32 words 1..3 == 1,2,3 iff fp32.
// ---------------------------------------------------------------------------
__global__ void detect_k(const void* inc, int* flag) {
  const float* f = (const float*)inc;
  float err = fabsf(f[1] - 1.f) + fabsf(f[2] - 2.f) + fabsf(f[3] - 3.f);
  *flag = (err < 0.5f) ? 0 : 1;   // 0 = fp32, 1 = bf16
}

// ---------------------------------------------------------------------------
// Weight convert: Wq(256x512), Wk(256x256), Wv(256x256), Wo(512x256) -> bf16.
// ---------------------------------------------------------------------------
template<typename T>
__device__ __forceinline__ void cvtw_body(const void* a, const void* b2,
                                          const void* c, const void* d,
                                          unsigned short* out) {
  int i = blockIdx.x * 256 + threadIdx.x;   // total 393216
  float v;
  if (i < 131072)      v = cvt(((const T*)a)[i]);
  else if (i < 196608) v = cvt(((const T*)b2)[i - 131072]);
  else if (i < 262144) v = cvt(((const T*)c)[i - 196608]);
  else                 v = cvt(((const T*)d)[i - 262144]);
  out[i] = f2bu(v);
}

__global__ __launch_bounds__(256) void cvtw_k(
    const int* __restrict__ flag, const void* a, const void* b2,
    const void* c, const void* d, unsigned short* out) {
  if (*flag) cvtw_body<bf16>(a, b2, c, d, out);
  else       cvtw_body<float>(a, b2, c, d, out);
}

// ---------------------------------------------------------------------------
// Transpose + convert: in T [b][K][M] (k-major) -> out bf16 [b][M][K].
// ---------------------------------------------------------------------------
template<typename T>
__device__ __forceinline__ void transpose_body(
    const void* inv, size_t ioff, size_t strideIn,
    unsigned short* out, size_t strideOut, int K, int M,
    unsigned int (*Ls)[33]) {
  const T* in = (const T*)inv + ioff + (size_t)blockIdx.z * strideIn;
  unsigned short* ob = out + (size_t)blockIdx.z * strideOut;
  const int m0 = blockIdx.x * 64, k0 = blockIdx.y * 64;
  const int tid = threadIdx.x;
  const int ml = tid & 63;
  int mrd = m0 + ml; if (mrd >= M) mrd = M - 1;
#pragma unroll
  for (int it = 0; it < 8; it++) {
    int kp = it * 4 + (tid >> 6);          // 0..31 (k-pair index)
    int k = k0 + kp * 2;
    float v0 = cvt(in[(size_t)k * M + mrd]);
    float v1 = cvt(in[(size_t)(k + 1) * M + mrd]);
    Ls[ml][kp] = (unsigned)f2bu(v0) | ((unsigned)f2bu(v1) << 16);
  }
  __syncthreads();
#pragma unroll
  for (int it = 0; it < 8; it++) {
    int idx = it * 256 + tid;
    int my = idx >> 5, kk = idx & 31;
    int m = m0 + my;
    if (m < M)
      *(unsigned*)&ob[(size_t)m * K + k0 + kk * 2] = Ls[my][kk];
  }
}

__global__ __launch_bounds__(256) void transpose_k(
    const int* __restrict__ flag, const void* in, size_t ioff, size_t strideIn,
    unsigned short* out, size_t strideOut, int K, int M) {
  __shared__ unsigned int Ls[64][33];
  if (*flag) transpose_body<bf16>(in, ioff, strideIn, out, strideOut, K, M, Ls);
  else       transpose_body<float>(in, ioff, strideIn, out, strideOut, K, M, Ls);
}

// ---------------------------------------------------------------------------
// MFMA GEMM core: D[m][n] = sum_k A[m][k] * B[n][k], bf16 in, fp32 accum.
// 128x128 tile, BK=32, 4 waves 2x2, 4x4 16x16x32 frags per wave.
// (Round-6 verified form: no register prefetch — that regressed in round 7.)
// ---------------------------------------------------------------------------
__device__ __forceinline__ void gemm_core(
    const unsigned short* __restrict__ Ab, int lda, int M,
    const unsigned short* __restrict__ Bb, int ldb, int N, int K,
    int m0, int n0,
    unsigned short (*As)[40], unsigned short (*Bs)[40],
    float4v (&acc)[4][4]) {
  const int tid = threadIdx.x;
  const int lane = tid & 63, w = tid >> 6;
  const int lq = lane & 15, quad = lane >> 4;
  const int wm = (w >> 1) * 64, wn = (w & 1) * 64;
  const int srow = tid >> 2;
  const int sch  = (tid & 3) * 8;

#pragma unroll
  for (int i = 0; i < 4; i++)
#pragma unroll
    for (int j = 0; j < 4; j++) acc[i][j] = (float4v){0.f, 0.f, 0.f, 0.f};

  for (int k0 = 0; k0 < K; k0 += 32) {
    uint4 va[2], vb[2];
#pragma unroll
    for (int hf = 0; hf < 2; hf++) {
      int ra = m0 + hf * 64 + srow; ra = (ra < M) ? ra : (M - 1);
      int rb = n0 + hf * 64 + srow; rb = (rb < N) ? rb : (N - 1);
      va[hf] = *(const uint4*)(Ab + (size_t)ra * lda + k0 + sch);
      vb[hf] = *(const uint4*)(Bb + (size_t)rb * ldb + k0 + sch);
    }
    __syncthreads();                       // prev iter done reading LDS
#pragma unroll
    for (int hf = 0; hf < 2; hf++) {
      *(uint4*)&As[hf * 64 + srow][sch] = va[hf];
      *(uint4*)&Bs[hf * 64 + srow][sch] = vb[hf];
    }
    __syncthreads();
    short8 af[4], bfr[4];
#pragma unroll
    for (int i = 0; i < 4; i++) {
      af[i]  = *(const short8*)&As[wm + i * 16 + lq][quad * 8];
      bfr[i] = *(const short8*)&Bs[wn + i * 16 + lq][quad * 8];
    }
#pragma unroll
    for (int i = 0; i < 4; i++)
#pragma unroll
      for (int j = 0; j < 4; j++)
        acc[i][j] = __builtin_amdgcn_mfma_f32_16x16x32_bf16(af[i], bfr[j], acc[i][j], 0, 0, 0);
  }
}

// ---------------------------------------------------------------------------
// Epilogue A (coalesced): bf16 C = acc + bias, optional fused RoPE.
// Stage 32x128 chunks in LDS ([32][136] ushort), then store full-line rows.
// RoPE (ropeT > 0, biasByM==0 callers only): output cols n0+wn..n0+wn+63 are
// exactly one head (n0,wn multiples of 64); thread holds pair (d, d+32) as
// (acc[i][jlo], acc[i][jlo+2]), jj = jlo*16+lq, t = m. Rotation in fp32
// before bf16 rounding. ang = inc[t]*inv_seq*theta[jj].
// (Verified in round 7: absmax 0.015625 with fusion active.)
// ---------------------------------------------------------------------------
template<typename T>
__device__ __forceinline__ void epi_store(
    float4v (&acc)[4][4], int m0, int n0, unsigned short* Cb, int ldc, int M, int N,
    const void* biasv, int biasByM, unsigned short* scr,
    const void* incv, const void* thetav, float inv_seq, int ropeT) {
  const T* bias = (const T*)biasv;
  const T* inc_ = (const T*)incv;
  const T* theta_ = (const T*)thetav;
  const int tid = threadIdx.x;
  const int lane = tid & 63, w = tid >> 6;
  const int lq = lane & 15, quad = lane >> 4;
  const int wm = (w >> 1) * 64, wn = (w & 1) * 64;
  const int rbase = (w >> 1) * 16 + quad * 4;
  const int lr = tid >> 3, ck = tid & 7;
  const int mbase = m0 + (lr >> 4) * 64 + (lr & 15);
#pragma unroll
  for (int i = 0; i < 4; i++) {
    __syncthreads();   // prior chunk (or gemm LDS reads) done
    if (ropeT > 0) {
#pragma unroll
      for (int jlo = 0; jlo < 2; jlo++) {
        float b1 = cvt(bias[n0 + wn + jlo * 16 + lq]);
        float b2 = cvt(bias[n0 + wn + (jlo + 2) * 16 + lq]);
        float th = cvt(theta_[jlo * 16 + lq]);
#pragma unroll
        for (int r = 0; r < 4; r++) {
          int t = m0 + wm + i * 16 + quad * 4 + r;
          int tt = (t < ropeT) ? t : (ropeT - 1);
          float ang = cvt(inc_[tt]) * inv_seq * th;
          float s, c;
          __sincosf(ang, &s, &c);
          float v1 = acc[i][jlo][r] + b1;
          float v2 = acc[i][jlo + 2][r] + b2;
          scr[(rbase + r) * 136 + wn + jlo * 16 + lq]       = f2bu(v1 * c - v2 * s);
          scr[(rbase + r) * 136 + wn + (jlo + 2) * 16 + lq] = f2bu(v1 * s + v2 * c);
        }
      }
    } else {
#pragma unroll
      for (int j = 0; j < 4; j++) {
        float bn_ = biasByM ? 0.f : cvt(bias[n0 + wn + j * 16 + lq]);
#pragma unroll
        for (int r = 0; r < 4; r++) {
          float bb = biasByM ? cvt(bias[m0 + wm + i * 16 + quad * 4 + r]) : bn_;
          scr[(rbase + r) * 136 + wn + j * 16 + lq] = f2bu(acc[i][j][r] + bb);
        }
      }
    }
    __syncthreads();
    int m = mbase + i * 16;
    if (m < M) {
#pragma unroll
      for (int u = 0; u < 2; u++) {
        int c = u * 64 + ck * 8;
        *(uint4*)&Cb[(size_t)m * ldc + n0 + c] = *(const uint4*)&scr[lr * 136 + c];
      }
    }
  }
}

__global__ __launch_bounds__(256) void gemm_bf(
    const int* __restrict__ flag,
    const unsigned short* __restrict__ A, size_t strideA, int lda, int M,
    const unsigned short* __restrict__ B, size_t strideB, int ldb, int N, int K,
    unsigned short* C, size_t strideC, int ldc,
    const void* bias, int biasByM,
    const void* inc, const void* theta, float inv_seq, int ropeT) {
  __shared__ __align__(16) unsigned char smem[20480];
  unsigned short (*As)[40] = (unsigned short (*)[40])smem;
  unsigned short (*Bs)[40] = (unsigned short (*)[40])(smem + 10240);
  const int bz = blockIdx.z;
  const int m0 = blockIdx.x * 128, n0 = blockIdx.y * 128;
  float4v acc[4][4];
  gemm_core(A + (size_t)bz * strideA, lda, M,
            B + (size_t)bz * strideB, ldb, N, K, m0, n0, As, Bs, acc);
  unsigned short* Cb = C + (size_t)bz * strideC;
  unsigned short* scr = (unsigned short*)smem;   // 32*136*2 = 8704 B
  if (*flag) epi_store<bf16>(acc, m0, n0, Cb, ldc, M, N, bias, biasByM, scr, inc, theta, inv_seq, ropeT);
  else       epi_store<float>(acc, m0, n0, Cb, ldc, M, N, bias, biasByM, scr, inc, theta, inv_seq, ropeT);
}

// ---------------------------------------------------------------------------
// Epilogue B: output projection. m = channel c (M=512), n = t (N=1000).
// Out[b][c][t] = (acc + bo[c] + x[b][c][t]) * lmask[b][t].
// Half-wave writes 512 B contiguous of one row (round-6 verified form —
// load/store adjacency here is what L2 write-combining needs; do not reorder).
// ---------------------------------------------------------------------------
template<typename T>
__device__ __forceinline__ void epi_out(
    float4v (&acc)[4][4], int m0, int n0, int bz, int M, int N,
    const void* biasv, const void* Xv, size_t xoffE,
    const void* lmv, size_t lmoffE, void* Outv, size_t ooffE, size_t strideO,
    float* scr) {
  const T* bias = (const T*)biasv;
  const T* X  = (const T*)Xv + xoffE;
  const T* lm = (const T*)lmv + lmoffE;
  T* Out      = (T*)Outv + ooffE;
  const int tid = threadIdx.x;
  const int lane = tid & 63, w = tid >> 6;
  const int lq = lane & 15, quad = lane >> 4;
  const int wm = (w >> 1) * 64, wn = (w & 1) * 64;
  const int rbase = (w >> 1) * 16 + quad * 4;
  const int col = (lane & 31) * 4;          // 0..124
  const int rw  = w * 2 + (lane >> 5);      // 0..7: row-within-8 for this half-wave
#pragma unroll
  for (int i = 0; i < 4; i++) {
    __syncthreads();
#pragma unroll
    for (int j = 0; j < 4; j++) {
#pragma unroll
      for (int r = 0; r < 4; r++) {
        int m = m0 + wm + i * 16 + quad * 4 + r;
        scr[(rbase + r) * 136 + wn + j * 16 + lq] = acc[i][j][r] + cvt(bias[m]);
      }
    }
    __syncthreads();
#pragma unroll
    for (int p = 0; p < 4; p++) {
      int lr2 = p * 8 + rw;                                    // 0..31
      int m = m0 + (lr2 >> 4) * 64 + (lr2 & 15) + i * 16;
      int n = n0 + col;
      if (m < M && n < N) {               // N % 4 == 0 -> full float4 or none
        size_t rowo = (size_t)bz * strideO + (size_t)m * TLAT;
        float4 sv = *(const float4*)&scr[lr2 * 136 + col];
        float4 vx = ld4(X + rowo + n);
        float4 vl = ld4(lm + (size_t)bz * TLAT + n);
        float4 v;
        v.x = (sv.x + vx.x) * vl.x;
        v.y = (sv.y + vx.y) * vl.y;
        v.z = (sv.z + vx.z) * vl.z;
        v.w = (sv.w + vx.w) * vl.w;
        st4(Out + rowo + n, v);
      }
    }
  }
}

__global__ __launch_bounds__(256) void gemm_bf_out(
    const int* __restrict__ flag,
    const unsigned short* __restrict__ A, size_t strideA, int lda, int M,
    const unsigned short* __restrict__ B, size_t strideB, int ldb, int N, int K,
    const void* bias, const void* X, size_t xoffE,
    const void* lmask, size_t lmoffE, void* Out, size_t ooffE, size_t strideO) {
  __shared__ __align__(16) unsigned char smem[20480];
  unsigned short (*As)[40] = (unsigned short (*)[40])smem;
  unsigned short (*Bs)[40] = (unsigned short (*)[40])(smem + 10240);

  // XCD swizzle (bijective, guarded on exact grid 4x8x64): one XCD gets all
  // 8 t-tiles of a (channel-tile, batch) so boundary lines merge in one L2.
  int bx = blockIdx.x, by = blockIdx.y, bz = blockIdx.z;
  if (gridDim.x == 4 && gridDim.y == 8 && gridDim.z == 64) {
    int lin = blockIdx.x + (blockIdx.y << 2) + (blockIdx.z << 5);
    int k = lin & 7, j = lin >> 3;
    by = j & 7; bx = (j >> 3) & 3; bz = (j >> 5) | (k << 3);
  }
  const int m0 = bx * 128, n0 = by * 128;

  float4v acc[4][4];
  gemm_core(A + (size_t)bz * strideA, lda, M,
            B + (size_t)bz * strideB, ldb, N, K, m0, n0, As, Bs, acc);
  float* scr = (float*)smem;                     // 32*136*4 = 17408 B
  if (*flag) epi_out<bf16>(acc, m0, n0, bz, M, N, bias, X, xoffE, lmask, lmoffE, Out, ooffE, strideO, scr);
  else       epi_out<float>(acc, m0, n0, bz, M, N, bias, X, xoffE, lmask, lmoffE, Out, ooffE, strideO, scr);
}

// ---------------------------------------------------------------------------
// MFMA flash attention. Block = (q-tile 64, h, b), 256 thr = 4 waves, each
// wave owns 16 q rows. Keys in 4 tiles of 128.
//   - Q fragments loaded straight from global into regs (no Qs tile).
//   - Ks/Vs/Ps XOR-swizzled (swz) so b128 frag reads hit all 32 banks.
// ---------------------------------------------------------------------------
__global__ __launch_bounds__(256) void attn_mfma(
    const unsigned short* __restrict__ Q, const unsigned short* __restrict__ K,
    const unsigned short* __restrict__ Vt, const int* __restrict__ tmask,
    unsigned short* __restrict__ AO) {
  const int b = blockIdx.z, h = blockIdx.y, q0 = blockIdx.x * 64;
  __shared__ unsigned short Ks[128][64];
  __shared__ unsigned short Vs[64][128];
  __shared__ unsigned short Ps[4][16][128];
  __shared__ float maskf[TTXT];

  const int tid = threadIdx.x;
  const int w = tid >> 6, lane = tid & 63;
  const int lq = lane & 15, quad = lane >> 4;

  // ---- Q frags straight from global (one-time, full 64B lines per quad) ----
  short8 qa0 = (short8){0, 0, 0, 0, 0, 0, 0, 0};
  short8 qa1 = (short8){0, 0, 0, 0, 0, 0, 0, 0};
  {
    int qrow = q0 + w * 16 + lq;
    if (qrow < TLAT) {
      const unsigned short* qp = Q + ((size_t)(b * TLAT + qrow) * TD_ + h * 64);
      qa0 = *(const short8*)(qp + quad * 8);
      qa1 = *(const short8*)(qp + 32 + quad * 8);
    }
  }
  maskf[tid]       = (float)tmask[b * TTXT + tid];
  maskf[tid + 256] = (float)tmask[b * TTXT + 256 + tid];

  float m_old[4] = {-1e30f, -1e30f, -1e30f, -1e30f};
  float l[4] = {0.f, 0.f, 0.f, 0.f};
  float4v Oacc[4];
#pragma unroll
  for (int i = 0; i < 4; i++) Oacc[i] = (float4v){0.f, 0.f, 0.f, 0.f};

  for (int kt = 0; kt < 4; kt++) {
    __syncthreads();                       // prior iter done reading Ks/Vs
#pragma unroll
    for (int it = 0; it < 4; it++) {       // K tile: 128 keys x 64 d
      int c = it * 256 + tid;
      int row = c >> 3, col = (c & 7) * 8;
      *(uint4*)&Ks[row][swz(row, col)] =
        *(const uint4*)(K + ((size_t)(b * TTXT + kt * 128 + row) * TD_ + h * 64 + col));
    }
#pragma unroll
    for (int it = 0; it < 4; it++) {       // V^T tile: 64 d x 128 keys
      int c = it * 256 + tid;
      int row = c >> 4, col = (c & 15) * 8;
      *(uint4*)&Vs[row][swz(row, col)] =
        *(const uint4*)(Vt + (((size_t)b * TD_ + h * 64 + row) * TTXT + kt * 128 + col));
    }
    __syncthreads();

    // ---- S = Q K^T for this wave's 16 rows x 128 keys ----
    float4v Sacc[8];
#pragma unroll
    for (int nt = 0; nt < 8; nt++) {
      int krow = nt * 16 + lq;
      short8 kb0 = *(const short8*)&Ks[krow][swz(krow, quad * 8)];
      short8 kb1 = *(const short8*)&Ks[krow][swz(krow, 32 + quad * 8)];
      float4v s = (float4v){0.f, 0.f, 0.f, 0.f};
      s = __builtin_amdgcn_mfma_f32_16x16x32_bf16(qa0, kb0, s, 0, 0, 0);
      s = __builtin_amdgcn_mfma_f32_16x16x32_bf16(qa1, kb1, s, 0, 0, 0);
      Sacc[nt] = s;
    }
    float mk[8];
#pragma unroll
    for (int nt = 0; nt < 8; nt++) mk[nt] = maskf[kt * 128 + nt * 16 + lq];

    // scale + mask (masked -> -1e30 so it can't raise the max)
#pragma unroll
    for (int nt = 0; nt < 8; nt++)
#pragma unroll
      for (int r = 0; r < 4; r++) {
        float sv = Sacc[nt][r] * SCALE_;
        Sacc[nt][r] = (mk[nt] != 0.f) ? sv : -1e30f;
      }

#pragma unroll
    for (int r = 0; r < 4; r++) {
      float mx = -1e30f;
#pragma unroll
      for (int nt = 0; nt < 8; nt++) mx = fmaxf(mx, Sacc[nt][r]);
      mx = fmaxf(mx, __shfl_xor(mx, 1));
      mx = fmaxf(mx, __shfl_xor(mx, 2));
      mx = fmaxf(mx, __shfl_xor(mx, 4));
      mx = fmaxf(mx, __shfl_xor(mx, 8));
      float mnew = fmaxf(m_old[r], mx);
      float alpha = __expf(m_old[r] - mnew);
      float ps = 0.f;
      int prow = quad * 4 + r;
#pragma unroll
      for (int nt = 0; nt < 8; nt++) {
        float p = (mk[nt] != 0.f) ? __expf(Sacc[nt][r] - mnew) : 0.f;
        ps += p;
        Ps[w][prow][swz(prow, nt * 16 + lq)] = f2bu(p);
      }
      ps += __shfl_xor(ps, 1);
      ps += __shfl_xor(ps, 2);
      ps += __shfl_xor(ps, 4);
      ps += __shfl_xor(ps, 8);
      l[r] = alpha * l[r] + ps;
      m_old[r] = mnew;
#pragma unroll
      for (int dt = 0; dt < 4; dt++) Oacc[dt][r] *= alpha;
    }

    // ---- O += P V (P from per-wave LDS; same-wave RAW, no barrier) ----
#pragma unroll
    for (int dt = 0; dt < 4; dt++) {
#pragma unroll
      for (int ks = 0; ks < 4; ks++) {
        short8 pa = *(const short8*)&Ps[w][lq][swz(lq, ks * 32 + quad * 8)];
        int vrow = dt * 16 + lq;
        short8 vb = *(const short8*)&Vs[vrow][swz(vrow, ks * 32 + quad * 8)];
        Oacc[dt] = __builtin_amdgcn_mfma_f32_16x16x32_bf16(pa, vb, Oacc[dt], 0, 0, 0);
      }
    }
  }

  // ---- normalize + store ----
#pragma unroll
  for (int r = 0; r < 4; r++) {
    int q = q0 + w * 16 + quad * 4 + r;
    if (q < TLAT) {
      float linv = 1.0f / fmaxf(l[r], 1e-30f);
#pragma unroll
      for (int dt = 0; dt < 4; dt++) {
        int d = h * 64 + dt * 16 + lq;
        AO[(size_t)(b * TLAT + q) * TD_ + d] = f2bu(Oacc[dt][r] * linv);
      }
    }
  }
}

extern "C" void kernel_launch(void* const* d_in, const int* in_sizes, int n_in,
                              void* d_out, int out_size, void* d_ws, size_t ws_size,
                              hipStream_t stream) {
  const void* x        = d_in[0];
  const void* text_emb = d_in[1];
  const void* lmask    = d_in[2];
  const int*  tmask    = (const int*)d_in[3];
  const void* Wq = d_in[4];
  const void* bq = d_in[5];
  const void* Wk = d_in[6];
  const void* bk = d_in[7];
  const void* Wv = d_in[8];
  const void* bv = d_in[9];
  const void* Wo = d_in[10];
  const void* bo = d_in[11];
  const void* theta = d_in[12];
  const void* inc   = d_in[13];

  int* dflag = (int*)d_ws;
  unsigned short* wbuf = (unsigned short*)((char*)d_ws + 256);  // 393216 elems
  unsigned short* scratch = wbuf + 393216;
  size_t used = 256 + (size_t)393216 * 2;
  size_t avail = (ws_size > used) ? ws_size - used : 0;

  // Per-batch bf16 scratch: xT(1000*512) + embT(512*256) + q(1000*256)
  //                       + k(512*256) + vT(256*512) + ao(1000*256)
  const size_t per_b_elems = 512000 + 131072 + 256000 + 131072 + 131072 + 256000;
  const size_t per_b_bytes = per_b_elems * 2;                   // ~2.84 MB
  int Bc = (int)(avail / per_b_bytes);
  if (Bc > B_) Bc = B_;
  if (Bc < 1) Bc = 1;

  unsigned short* xT   = scratch;
  unsigned short* embT = xT   + (size_t)Bc * 512000;
  unsigned short* qb   = embT + (size_t)Bc * 131072;
  unsigned short* kb   = qb   + (size_t)Bc * 256000;
  unsigned short* vtb  = kb   + (size_t)Bc * 131072;
  unsigned short* aob  = vtb  + (size_t)Bc * 131072;

  detect_k<<<1, 1, 0, stream>>>(inc, dflag);
  cvtw_k<<<1536, 256, 0, stream>>>(dflag, Wq, Wk, Wv, Wo, wbuf);
  const unsigned short* Wqb = wbuf;
  const unsigned short* Wkb = wbuf + 131072;
  const unsigned short* Wvb = wbuf + 196608;
  const unsigned short* Wob = wbuf + 262144;

  for (int b0 = 0; b0 < B_; b0 += Bc) {
    int bn = B_ - b0; if (bn > Bc) bn = Bc;
    size_t xoffE = (size_t)b0 * CH_ * TLAT;       // fp-elem offset into x
    size_t eoffE = (size_t)b0 * TD_ * TTXT;       // fp-elem offset into text_emb

    // x[b][512][1000] -> xT[b][1000][512] bf16 ; emb[b][256][512] -> embT[b][512][256]
    transpose_k<<<dim3(16, 8, bn), 256, 0, stream>>>(dflag, x, xoffE, 512000,
                                                     xT, 512000, CH_, TLAT);
    transpose_k<<<dim3(8, 4, bn), 256, 0, stream>>>(dflag, text_emb, eoffE, 131072,
                                                    embT, 131072, TD_, TTXT);

    // q[t][d] = xT[t][c] . Wq[d][c] + bq[d], RoPE fused (T=1000)
    gemm_bf<<<dim3(8, 2, bn), 256, 0, stream>>>(dflag, xT, 512000, 512, TLAT,
                                                Wqb, 0, 512, TD_, CH_,
                                                qb, 256000, TD_, bq, 0,
                                                inc, theta, 1.0f / TLAT, TLAT);
    // k[t][d] = embT[t][d'] . Wk[d][d'] + bk[d], RoPE fused (T=512)
    gemm_bf<<<dim3(4, 2, bn), 256, 0, stream>>>(dflag, embT, 131072, 256, TTXT,
                                                Wkb, 0, 256, TD_, TD_,
                                                kb, 131072, TD_, bk, 0,
                                                inc, theta, 1.0f / TTXT, TTXT);
    // vT[d][t] = Wv[d][d'] . embT[t][d'] + bv[d]   (bias by m, no rope)
    gemm_bf<<<dim3(2, 4, bn), 256, 0, stream>>>(dflag, Wvb, 0, 256, TD_,
                                                embT, 131072, 256, TTXT, TD_,
                                                vtb, 131072, TTXT, bv, 1,
                                                inc, theta, 0.f, 0);

    attn_mfma<<<dim3(16, H_, bn), 256, 0, stream>>>(qb, kb, vtb,
                                                    tmask + (size_t)b0 * TTXT, aob);

    // Out[c][t] = (Wo[c][d] . ao[t][d] + bo[c] + x[c][t]) * lmask[t]
    gemm_bf_out<<<dim3(4, 8, bn), 256, 0, stream>>>(dflag, Wob, 0, 256, CH_,
                                                    aob, 256000, 256, TLAT, TD_,
                                                    bo, x, xoffE,
                                                    lmask, (size_t)b0 * TLAT,
                                                    d_out, xoffE, (size_t)CH_ * TLAT);
  }
}

// Round 9
// 676.213 us; speedup vs baseline: 1.3985x; 1.0095x over previous
//
#include <hip/hip_runtime.h>
#include <hip/hip_bf16.h>

typedef __hip_bfloat16 bf16;
typedef __attribute__((ext_vector_type(8))) short short8;
typedef __attribute__((ext_vector_type(4))) float float4v;

#define B_    64
#define CH_   512
#define TD_   256
#define H_    4
#define DH_   64
#define TLAT  1000
#define TTXT  512
#define SCALE_ 0.0625f

__device__ __forceinline__ float cvt(float x) { return x; }
__device__ __forceinline__ float cvt(bf16 x)  { return __bfloat162float(x); }
__device__ __forceinline__ void stv(float* p, float v) { *p = v; }
__device__ __forceinline__ void stv(bf16* p, float v)  { *p = __float2bfloat16(v); }

__device__ __forceinline__ unsigned short f2bu(float f) {
  bf16 h = __float2bfloat16(f);
  unsigned short u; __builtin_memcpy(&u, &h, 2); return u;
}
__device__ __forceinline__ float bu2f(unsigned short u) {
  bf16 h; __builtin_memcpy(&h, &u, 2); return __bfloat162float(h);
}

// LDS XOR swizzle (T2/G4): element (row,col) -> col ^ ((row&7)<<3), ushort
// units. Flips 16B-chunk index bits only, preserves 16B alignment.
__device__ __forceinline__ int swz(int row, int col) {
  return col ^ ((row & 7) << 3);
}

// Vector load/store helpers (4 elems), dtype-polymorphic.
__device__ __forceinline__ float4 ld4(const float* p) { return *(const float4*)p; }
__device__ __forceinline__ float4 ld4(const bf16* p) {
  ushort4 u = *(const ushort4*)p;
  return make_float4(bu2f(u.x), bu2f(u.y), bu2f(u.z), bu2f(u.w));
}
__device__ __forceinline__ void st4(float* p, float4 v) { *(float4*)p = v; }
__device__ __forceinline__ void st4(bf16* p, float4 v) {
  ushort4 u = make_ushort4(f2bu(v.x), f2bu(v.y), f2bu(v.z), f2bu(v.w));
  *(ushort4*)p = u;
}

// ---------------------------------------------------------------------------
// dtype probe: increments = arange(1000). fp32 words 1..3 == 1,2,3 iff fp32.
// ---------------------------------------------------------------------------
__global__ void detect_k(const void* inc, int* flag) {
  const float* f = (const float*)inc;
  float err = fabsf(f[1] - 1.f) + fabsf(f[2] - 2.f) + fabsf(f[3] - 3.f);
  *flag = (err < 0.5f) ? 0 : 1;   // 0 = fp32, 1 = bf16
}

// ---------------------------------------------------------------------------
// Weight convert: Wq(256x512), Wk(256x256), Wv(256x256), Wo(512x256) -> bf16.
// ---------------------------------------------------------------------------
template<typename T>
__device__ __forceinline__ void cvtw_body(const void* a, const void* b2,
                                          const void* c, const void* d,
                                          unsigned short* out) {
  int i = blockIdx.x * 256 + threadIdx.x;   // total 393216
  float v;
  if (i < 131072)      v = cvt(((const T*)a)[i]);
  else if (i < 196608) v = cvt(((const T*)b2)[i - 131072]);
  else if (i < 262144) v = cvt(((const T*)c)[i - 196608]);
  else                 v = cvt(((const T*)d)[i - 262144]);
  out[i] = f2bu(v);
}

__global__ __launch_bounds__(256) void cvtw_k(
    const int* __restrict__ flag, const void* a, const void* b2,
    const void* c, const void* d, unsigned short* out) {
  if (*flag) cvtw_body<bf16>(a, b2, c, d, out);
  else       cvtw_body<float>(a, b2, c, d, out);
}

// ---------------------------------------------------------------------------
// Transpose + convert: in T [b][K][M] (k-major) -> out bf16 [b][M][K].
// ---------------------------------------------------------------------------
template<typename T>
__device__ __forceinline__ void transpose_body(
    const void* inv, size_t ioff, size_t strideIn,
    unsigned short* out, size_t strideOut, int K, int M,
    unsigned int (*Ls)[33]) {
  const T* in = (const T*)inv + ioff + (size_t)blockIdx.z * strideIn;
  unsigned short* ob = out + (size_t)blockIdx.z * strideOut;
  const int m0 = blockIdx.x * 64, k0 = blockIdx.y * 64;
  const int tid = threadIdx.x;
  const int ml = tid & 63;
  int mrd = m0 + ml; if (mrd >= M) mrd = M - 1;
#pragma unroll
  for (int it = 0; it < 8; it++) {
    int kp = it * 4 + (tid >> 6);          // 0..31 (k-pair index)
    int k = k0 + kp * 2;
    float v0 = cvt(in[(size_t)k * M + mrd]);
    float v1 = cvt(in[(size_t)(k + 1) * M + mrd]);
    Ls[ml][kp] = (unsigned)f2bu(v0) | ((unsigned)f2bu(v1) << 16);
  }
  __syncthreads();
#pragma unroll
  for (int it = 0; it < 8; it++) {
    int idx = it * 256 + tid;
    int my = idx >> 5, kk = idx & 31;
    int m = m0 + my;
    if (m < M)
      *(unsigned*)&ob[(size_t)m * K + k0 + kk * 2] = Ls[my][kk];
  }
}

__global__ __launch_bounds__(256) void transpose_k(
    const int* __restrict__ flag, const void* in, size_t ioff, size_t strideIn,
    unsigned short* out, size_t strideOut, int K, int M) {
  __shared__ unsigned int Ls[64][33];
  if (*flag) transpose_body<bf16>(in, ioff, strideIn, out, strideOut, K, M, Ls);
  else       transpose_body<float>(in, ioff, strideIn, out, strideOut, K, M, Ls);
}

// ---------------------------------------------------------------------------
// MFMA GEMM core: D[m][n] = sum_k A[m][k] * B[n][k], bf16 in, fp32 accum.
// 128x128 tile, BK=32, 4 waves 2x2, 4x4 16x16x32 frags per wave.
// (Round-6 verified form: no register prefetch — that regressed in round 7.)
// ---------------------------------------------------------------------------
__device__ __forceinline__ void gemm_core(
    const unsigned short* __restrict__ Ab, int lda, int M,
    const unsigned short* __restrict__ Bb, int ldb, int N, int K,
    int m0, int n0,
    unsigned short (*As)[40], unsigned short (*Bs)[40],
    float4v (&acc)[4][4]) {
  const int tid = threadIdx.x;
  const int lane = tid & 63, w = tid >> 6;
  const int lq = lane & 15, quad = lane >> 4;
  const int wm = (w >> 1) * 64, wn = (w & 1) * 64;
  const int srow = tid >> 2;
  const int sch  = (tid & 3) * 8;

#pragma unroll
  for (int i = 0; i < 4; i++)
#pragma unroll
    for (int j = 0; j < 4; j++) acc[i][j] = (float4v){0.f, 0.f, 0.f, 0.f};

  for (int k0 = 0; k0 < K; k0 += 32) {
    uint4 va[2], vb[2];
#pragma unroll
    for (int hf = 0; hf < 2; hf++) {
      int ra = m0 + hf * 64 + srow; ra = (ra < M) ? ra : (M - 1);
      int rb = n0 + hf * 64 + srow; rb = (rb < N) ? rb : (N - 1);
      va[hf] = *(const uint4*)(Ab + (size_t)ra * lda + k0 + sch);
      vb[hf] = *(const uint4*)(Bb + (size_t)rb * ldb + k0 + sch);
    }
    __syncthreads();                       // prev iter done reading LDS
#pragma unroll
    for (int hf = 0; hf < 2; hf++) {
      *(uint4*)&As[hf * 64 + srow][sch] = va[hf];
      *(uint4*)&Bs[hf * 64 + srow][sch] = vb[hf];
    }
    __syncthreads();
    short8 af[4], bfr[4];
#pragma unroll
    for (int i = 0; i < 4; i++) {
      af[i]  = *(const short8*)&As[wm + i * 16 + lq][quad * 8];
      bfr[i] = *(const short8*)&Bs[wn + i * 16 + lq][quad * 8];
    }
#pragma unroll
    for (int i = 0; i < 4; i++)
#pragma unroll
      for (int j = 0; j < 4; j++)
        acc[i][j] = __builtin_amdgcn_mfma_f32_16x16x32_bf16(af[i], bfr[j], acc[i][j], 0, 0, 0);
  }
}

// ---------------------------------------------------------------------------
// Epilogue A (coalesced): bf16 C = acc + bias, optional fused RoPE.
// Stage 32x128 chunks in LDS ([32][136] ushort), then store full-line rows.
// RoPE (ropeT > 0, biasByM==0 callers only): output cols n0+wn..n0+wn+63 are
// exactly one head (n0,wn multiples of 64); thread holds pair (d, d+32) as
// (acc[i][jlo], acc[i][jlo+2]), jj = jlo*16+lq, t = m. Rotation in fp32
// before bf16 rounding. ang = inc[t]*inv_seq*theta[jj].
// ---------------------------------------------------------------------------
template<typename T>
__device__ __forceinline__ void epi_store(
    float4v (&acc)[4][4], int m0, int n0, unsigned short* Cb, int ldc, int M, int N,
    const void* biasv, int biasByM, unsigned short* scr,
    const void* incv, const void* thetav, float inv_seq, int ropeT) {
  const T* bias = (const T*)biasv;
  const T* inc_ = (const T*)incv;
  const T* theta_ = (const T*)thetav;
  const int tid = threadIdx.x;
  const int lane = tid & 63, w = tid >> 6;
  const int lq = lane & 15, quad = lane >> 4;
  const int wm = (w >> 1) * 64, wn = (w & 1) * 64;
  const int rbase = (w >> 1) * 16 + quad * 4;
  const int lr = tid >> 3, ck = tid & 7;
  const int mbase = m0 + (lr >> 4) * 64 + (lr & 15);
#pragma unroll
  for (int i = 0; i < 4; i++) {
    __syncthreads();   // prior chunk (or gemm LDS reads) done
    if (ropeT > 0) {
#pragma unroll
      for (int jlo = 0; jlo < 2; jlo++) {
        float b1 = cvt(bias[n0 + wn + jlo * 16 + lq]);
        float b2 = cvt(bias[n0 + wn + (jlo + 2) * 16 + lq]);
        float th = cvt(theta_[jlo * 16 + lq]);
#pragma unroll
        for (int r = 0; r < 4; r++) {
          int t = m0 + wm + i * 16 + quad * 4 + r;
          int tt = (t < ropeT) ? t : (ropeT - 1);
          float ang = cvt(inc_[tt]) * inv_seq * th;
          float s, c;
          __sincosf(ang, &s, &c);
          float v1 = acc[i][jlo][r] + b1;
          float v2 = acc[i][jlo + 2][r] + b2;
          scr[(rbase + r) * 136 + wn + jlo * 16 + lq]       = f2bu(v1 * c - v2 * s);
          scr[(rbase + r) * 136 + wn + (jlo + 2) * 16 + lq] = f2bu(v1 * s + v2 * c);
        }
      }
    } else {
#pragma unroll
      for (int j = 0; j < 4; j++) {
        float bn_ = biasByM ? 0.f : cvt(bias[n0 + wn + j * 16 + lq]);
#pragma unroll
        for (int r = 0; r < 4; r++) {
          float bb = biasByM ? cvt(bias[m0 + wm + i * 16 + quad * 4 + r]) : bn_;
          scr[(rbase + r) * 136 + wn + j * 16 + lq] = f2bu(acc[i][j][r] + bb);
        }
      }
    }
    __syncthreads();
    int m = mbase + i * 16;
    if (m < M) {
#pragma unroll
      for (int u = 0; u < 2; u++) {
        int c = u * 64 + ck * 8;
        *(uint4*)&Cb[(size_t)m * ldc + n0 + c] = *(const uint4*)&scr[lr * 136 + c];
      }
    }
  }
}

__global__ __launch_bounds__(256) void gemm_bf(
    const int* __restrict__ flag,
    const unsigned short* __restrict__ A, size_t strideA, int lda, int M,
    const unsigned short* __restrict__ B, size_t strideB, int ldb, int N, int K,
    unsigned short* C, size_t strideC, int ldc,
    const void* bias, int biasByM,
    const void* inc, const void* theta, float inv_seq, int ropeT) {
  __shared__ __align__(16) unsigned char smem[20480];
  unsigned short (*As)[40] = (unsigned short (*)[40])smem;
  unsigned short (*Bs)[40] = (unsigned short (*)[40])(smem + 10240);

  // XCD-grouping swizzles (bijective, guarded on exact grids; correctness
  // does not depend on the dispatch heuristic):
  //  - k-proj (4,2,64): 2 n-blocks sharing an A-slab -> same XCD.
  //  - v-proj (2,4,64): 2 m-blocks sharing a B-slab -> same XCD.
  //  - q-proj (8,2,64): GX=8 already co-locates pairs mod 8; no remap.
  int bx = blockIdx.x, by = blockIdx.y, bz = blockIdx.z;
  if (gridDim.x == 4 && gridDim.y == 2 && gridDim.z == 64) {
    int s = blockIdx.x + (blockIdx.y << 2) + (blockIdx.z << 3);
    int xcd = s & 7, t = s >> 3;
    by = t & 1;
    int g = xcd + ((t >> 1) << 3);
    bx = g & 3; bz = g >> 2;
  } else if (gridDim.x == 2 && gridDim.y == 4 && gridDim.z == 64) {
    int s = blockIdx.x + (blockIdx.y << 1) + (blockIdx.z << 3);
    int xcd = s & 7, t = s >> 3;
    bx = t & 1;
    int g = xcd + ((t >> 1) << 3);
    by = g & 3; bz = g >> 2;
  }
  const int m0 = bx * 128, n0 = by * 128;

  float4v acc[4][4];
  gemm_core(A + (size_t)bz * strideA, lda, M,
            B + (size_t)bz * strideB, ldb, N, K, m0, n0, As, Bs, acc);
  unsigned short* Cb = C + (size_t)bz * strideC;
  unsigned short* scr = (unsigned short*)smem;   // 32*136*2 = 8704 B
  if (*flag) epi_store<bf16>(acc, m0, n0, Cb, ldc, M, N, bias, biasByM, scr, inc, theta, inv_seq, ropeT);
  else       epi_store<float>(acc, m0, n0, Cb, ldc, M, N, bias, biasByM, scr, inc, theta, inv_seq, ropeT);
}

// ---------------------------------------------------------------------------
// Epilogue B: output projection. m = channel c (M=512), n = t (N=1000).
// Out[b][c][t] = (acc + bo[c] + x[b][c][t]) * lmask[b][t].
// Half-wave writes 512 B contiguous of one row (round-6 verified form —
// load/store adjacency here is what L2 write-combining needs; do not reorder).
// ---------------------------------------------------------------------------
template<typename T>
__device__ __forceinline__ void epi_out(
    float4v (&acc)[4][4], int m0, int n0, int bz, int M, int N,
    const void* biasv, const void* Xv, size_t xoffE,
    const void* lmv, size_t lmoffE, void* Outv, size_t ooffE, size_t strideO,
    float* scr) {
  const T* bias = (const T*)biasv;
  const T* X  = (const T*)Xv + xoffE;
  const T* lm = (const T*)lmv + lmoffE;
  T* Out      = (T*)Outv + ooffE;
  const int tid = threadIdx.x;
  const int lane = tid & 63, w = tid >> 6;
  const int lq = lane & 15, quad = lane >> 4;
  const int wm = (w >> 1) * 64, wn = (w & 1) * 64;
  const int rbase = (w >> 1) * 16 + quad * 4;
  const int col = (lane & 31) * 4;          // 0..124
  const int rw  = w * 2 + (lane >> 5);      // 0..7: row-within-8 for this half-wave
#pragma unroll
  for (int i = 0; i < 4; i++) {
    __syncthreads();
#pragma unroll
    for (int j = 0; j < 4; j++) {
#pragma unroll
      for (int r = 0; r < 4; r++) {
        int m = m0 + wm + i * 16 + quad * 4 + r;
        scr[(rbase + r) * 136 + wn + j * 16 + lq] = acc[i][j][r] + cvt(bias[m]);
      }
    }
    __syncthreads();
#pragma unroll
    for (int p = 0; p < 4; p++) {
      int lr2 = p * 8 + rw;                                    // 0..31
      int m = m0 + (lr2 >> 4) * 64 + (lr2 & 15) + i * 16;
      int n = n0 + col;
      if (m < M && n < N) {               // N % 4 == 0 -> full float4 or none
        size_t rowo = (size_t)bz * strideO + (size_t)m * TLAT;
        float4 sv = *(const float4*)&scr[lr2 * 136 + col];
        float4 vx = ld4(X + rowo + n);
        float4 vl = ld4(lm + (size_t)bz * TLAT + n);
        float4 v;
        v.x = (sv.x + vx.x) * vl.x;
        v.y = (sv.y + vx.y) * vl.y;
        v.z = (sv.z + vx.z) * vl.z;
        v.w = (sv.w + vx.w) * vl.w;
        st4(Out + rowo + n, v);
      }
    }
  }
}

__global__ __launch_bounds__(256) void gemm_bf_out(
    const int* __restrict__ flag,
    const unsigned short* __restrict__ A, size_t strideA, int lda, int M,
    const unsigned short* __restrict__ B, size_t strideB, int ldb, int N, int K,
    const void* bias, const void* X, size_t xoffE,
    const void* lmask, size_t lmoffE, void* Out, size_t ooffE, size_t strideO) {
  __shared__ __align__(16) unsigned char smem[20480];
  unsigned short (*As)[40] = (unsigned short (*)[40])smem;
  unsigned short (*Bs)[40] = (unsigned short (*)[40])(smem + 10240);

  // XCD swizzle (bijective, guarded on exact grid 4x8x64): one XCD gets all
  // 8 t-tiles of a (channel-tile, batch) so boundary lines merge in one L2.
  int bx = blockIdx.x, by = blockIdx.y, bz = blockIdx.z;
  if (gridDim.x == 4 && gridDim.y == 8 && gridDim.z == 64) {
    int lin = blockIdx.x + (blockIdx.y << 2) + (blockIdx.z << 5);
    int k = lin & 7, j = lin >> 3;
    by = j & 7; bx = (j >> 3) & 3; bz = (j >> 5) | (k << 3);
  }
  const int m0 = bx * 128, n0 = by * 128;

  float4v acc[4][4];
  gemm_core(A + (size_t)bz * strideA, lda, M,
            B + (size_t)bz * strideB, ldb, N, K, m0, n0, As, Bs, acc);
  float* scr = (float*)smem;                     // 32*136*4 = 17408 B
  if (*flag) epi_out<bf16>(acc, m0, n0, bz, M, N, bias, X, xoffE, lmask, lmoffE, Out, ooffE, strideO, scr);
  else       epi_out<float>(acc, m0, n0, bz, M, N, bias, X, xoffE, lmask, lmoffE, Out, ooffE, strideO, scr);
}

// ---------------------------------------------------------------------------
// MFMA flash attention. Block = (q-tile 64, h, b), 256 thr = 4 waves, each
// wave owns 16 q rows. Keys in 4 tiles of 128.
//   - Q fragments loaded straight from global into regs (no Qs tile).
//   - Ks/Vs/Ps XOR-swizzled (swz) so b128 frag reads hit all 32 banks.
//   - XCD-grouping: all 16 q-blocks of one (h,b) on one XCD so K/V stay in
//     that XCD's L2 across their 16x re-staging (bijective, grid-guarded).
// ---------------------------------------------------------------------------
__global__ __launch_bounds__(256) void attn_mfma(
    const unsigned short* __restrict__ Q, const unsigned short* __restrict__ K,
    const unsigned short* __restrict__ Vt, const int* __restrict__ tmask,
    unsigned short* __restrict__ AO) {
  int bxq = blockIdx.x, hh = blockIdx.y, bb = blockIdx.z;
  if (gridDim.x == 16 && gridDim.y == 4 && gridDim.z == 64) {
    int s = blockIdx.x + (blockIdx.y << 4) + (blockIdx.z << 6);
    int xcd = s & 7, t = s >> 3;
    bxq = t & 15;
    int g = xcd + ((t >> 4) << 3);
    hh = g & 3; bb = g >> 2;
  }
  const int b = bb, h = hh, q0 = bxq * 64;
  __shared__ unsigned short Ks[128][64];
  __shared__ unsigned short Vs[64][128];
  __shared__ unsigned short Ps[4][16][128];
  __shared__ float maskf[TTXT];

  const int tid = threadIdx.x;
  const int w = tid >> 6, lane = tid & 63;
  const int lq = lane & 15, quad = lane >> 4;

  // ---- Q frags straight from global (one-time, full 64B lines per quad) ----
  short8 qa0 = (short8){0, 0, 0, 0, 0, 0, 0, 0};
  short8 qa1 = (short8){0, 0, 0, 0, 0, 0, 0, 0};
  {
    int qrow = q0 + w * 16 + lq;
    if (qrow < TLAT) {
      const unsigned short* qp = Q + ((size_t)(b * TLAT + qrow) * TD_ + h * 64);
      qa0 = *(const short8*)(qp + quad * 8);
      qa1 = *(const short8*)(qp + 32 + quad * 8);
    }
  }
  maskf[tid]       = (float)tmask[b * TTXT + tid];
  maskf[tid + 256] = (float)tmask[b * TTXT + 256 + tid];

  float m_old[4] = {-1e30f, -1e30f, -1e30f, -1e30f};
  float l[4] = {0.f, 0.f, 0.f, 0.f};
  float4v Oacc[4];
#pragma unroll
  for (int i = 0; i < 4; i++) Oacc[i] = (float4v){0.f, 0.f, 0.f, 0.f};

  for (int kt = 0; kt < 4; kt++) {
    __syncthreads();                       // prior iter done reading Ks/Vs
#pragma unroll
    for (int it = 0; it < 4; it++) {       // K tile: 128 keys x 64 d
      int c = it * 256 + tid;
      int row = c >> 3, col = (c & 7) * 8;
      *(uint4*)&Ks[row][swz(row, col)] =
        *(const uint4*)(K + ((size_t)(b * TTXT + kt * 128 + row) * TD_ + h * 64 + col));
    }
#pragma unroll
    for (int it = 0; it < 4; it++) {       // V^T tile: 64 d x 128 keys
      int c = it * 256 + tid;
      int row = c >> 4, col = (c & 15) * 8;
      *(uint4*)&Vs[row][swz(row, col)] =
        *(const uint4*)(Vt + (((size_t)b * TD_ + h * 64 + row) * TTXT + kt * 128 + col));
    }
    __syncthreads();

    // ---- S = Q K^T for this wave's 16 rows x 128 keys ----
    float4v Sacc[8];
#pragma unroll
    for (int nt = 0; nt < 8; nt++) {
      int krow = nt * 16 + lq;
      short8 kb0 = *(const short8*)&Ks[krow][swz(krow, quad * 8)];
      short8 kb1 = *(const short8*)&Ks[krow][swz(krow, 32 + quad * 8)];
      float4v s = (float4v){0.f, 0.f, 0.f, 0.f};
      s = __builtin_amdgcn_mfma_f32_16x16x32_bf16(qa0, kb0, s, 0, 0, 0);
      s = __builtin_amdgcn_mfma_f32_16x16x32_bf16(qa1, kb1, s, 0, 0, 0);
      Sacc[nt] = s;
    }
    float mk[8];
#pragma unroll
    for (int nt = 0; nt < 8; nt++) mk[nt] = maskf[kt * 128 + nt * 16 + lq];

    // scale + mask (masked -> -1e30 so it can't raise the max)
#pragma unroll
    for (int nt = 0; nt < 8; nt++)
#pragma unroll
      for (int r = 0; r < 4; r++) {
        float sv = Sacc[nt][r] * SCALE_;
        Sacc[nt][r] = (mk[nt] != 0.f) ? sv : -1e30f;
      }

#pragma unroll
    for (int r = 0; r < 4; r++) {
      float mx = -1e30f;
#pragma unroll
      for (int nt = 0; nt < 8; nt++) mx = fmaxf(mx, Sacc[nt][r]);
      mx = fmaxf(mx, __shfl_xor(mx, 1));
      mx = fmaxf(mx, __shfl_xor(mx, 2));
      mx = fmaxf(mx, __shfl_xor(mx, 4));
      mx = fmaxf(mx, __shfl_xor(mx, 8));
      float mnew = fmaxf(m_old[r], mx);
      float alpha = __expf(m_old[r] - mnew);
      float ps = 0.f;
      int prow = quad * 4 + r;
#pragma unroll
      for (int nt = 0; nt < 8; nt++) {
        float p = (mk[nt] != 0.f) ? __expf(Sacc[nt][r] - mnew) : 0.f;
        ps += p;
        Ps[w][prow][swz(prow, nt * 16 + lq)] = f2bu(p);
      }
      ps += __shfl_xor(ps, 1);
      ps += __shfl_xor(ps, 2);
      ps += __shfl_xor(ps, 4);
      ps += __shfl_xor(ps, 8);
      l[r] = alpha * l[r] + ps;
      m_old[r] = mnew;
#pragma unroll
      for (int dt = 0; dt < 4; dt++) Oacc[dt][r] *= alpha;
    }

    // ---- O += P V (P from per-wave LDS; same-wave RAW, no barrier) ----
#pragma unroll
    for (int dt = 0; dt < 4; dt++) {
#pragma unroll
      for (int ks = 0; ks < 4; ks++) {
        short8 pa = *(const short8*)&Ps[w][lq][swz(lq, ks * 32 + quad * 8)];
        int vrow = dt * 16 + lq;
        short8 vb = *(const short8*)&Vs[vrow][swz(vrow, ks * 32 + quad * 8)];
        Oacc[dt] = __builtin_amdgcn_mfma_f32_16x16x32_bf16(pa, vb, Oacc[dt], 0, 0, 0);
      }
    }
  }

  // ---- normalize + store ----
#pragma unroll
  for (int r = 0; r < 4; r++) {
    int q = q0 + w * 16 + quad * 4 + r;
    if (q < TLAT) {
      float linv = 1.0f / fmaxf(l[r], 1e-30f);
#pragma unroll
      for (int dt = 0; dt < 4; dt++) {
        int d = h * 64 + dt * 16 + lq;
        AO[(size_t)(b * TLAT + q) * TD_ + d] = f2bu(Oacc[dt][r] * linv);
      }
    }
  }
}

extern "C" void kernel_launch(void* const* d_in, const int* in_sizes, int n_in,
                              void* d_out, int out_size, void* d_ws, size_t ws_size,
                              hipStream_t stream) {
  const void* x        = d_in[0];
  const void* text_emb = d_in[1];
  const void* lmask    = d_in[2];
  const int*  tmask    = (const int*)d_in[3];
  const void* Wq = d_in[4];
  const void* bq = d_in[5];
  const void* Wk = d_in[6];
  const void* bk = d_in[7];
  const void* Wv = d_in[8];
  const void* bv = d_in[9];
  const void* Wo = d_in[10];
  const void* bo = d_in[11];
  const void* theta = d_in[12];
  const void* inc   = d_in[13];

  int* dflag = (int*)d_ws;
  unsigned short* wbuf = (unsigned short*)((char*)d_ws + 256);  // 393216 elems
  unsigned short* scratch = wbuf + 393216;
  size_t used = 256 + (size_t)393216 * 2;
  size_t avail = (ws_size > used) ? ws_size - used : 0;

  // Per-batch bf16 scratch: xT(1000*512) + embT(512*256) + q(1000*256)
  //                       + k(512*256) + vT(256*512) + ao(1000*256)
  const size_t per_b_elems = 512000 + 131072 + 256000 + 131072 + 131072 + 256000;
  const size_t per_b_bytes = per_b_elems * 2;                   // ~2.84 MB
  int Bc = (int)(avail / per_b_bytes);
  if (Bc > B_) Bc = B_;
  if (Bc < 1) Bc = 1;

  unsigned short* xT   = scratch;
  unsigned short* embT = xT   + (size_t)Bc * 512000;
  unsigned short* qb   = embT + (size_t)Bc * 131072;
  unsigned short* kb   = qb   + (size_t)Bc * 256000;
  unsigned short* vtb  = kb   + (size_t)Bc * 131072;
  unsigned short* aob  = vtb  + (size_t)Bc * 131072;

  detect_k<<<1, 1, 0, stream>>>(inc, dflag);
  cvtw_k<<<1536, 256, 0, stream>>>(dflag, Wq, Wk, Wv, Wo, wbuf);
  const unsigned short* Wqb = wbuf;
  const unsigned short* Wkb = wbuf + 131072;
  const unsigned short* Wvb = wbuf + 196608;
  const unsigned short* Wob = wbuf + 262144;

  for (int b0 = 0; b0 < B_; b0 += Bc) {
    int bn = B_ - b0; if (bn > Bc) bn = Bc;
    size_t xoffE = (size_t)b0 * CH_ * TLAT;       // fp-elem offset into x
    size_t eoffE = (size_t)b0 * TD_ * TTXT;       // fp-elem offset into text_emb

    // x[b][512][1000] -> xT[b][1000][512] bf16 ; emb[b][256][512] -> embT[b][512][256]
    transpose_k<<<dim3(16, 8, bn), 256, 0, stream>>>(dflag, x, xoffE, 512000,
                                                     xT, 512000, CH_, TLAT);
    transpose_k<<<dim3(8, 4, bn), 256, 0, stream>>>(dflag, text_emb, eoffE, 131072,
                                                    embT, 131072, TD_, TTXT);

    // q[t][d] = xT[t][c] . Wq[d][c] + bq[d], RoPE fused (T=1000)
    gemm_bf<<<dim3(8, 2, bn), 256, 0, stream>>>(dflag, xT, 512000, 512, TLAT,
                                                Wqb, 0, 512, TD_, CH_,
                                                qb, 256000, TD_, bq, 0,
                                                inc, theta, 1.0f / TLAT, TLAT);
    // k[t][d] = embT[t][d'] . Wk[d][d'] + bk[d], RoPE fused (T=512)
    gemm_bf<<<dim3(4, 2, bn), 256, 0, stream>>>(dflag, embT, 131072, 256, TTXT,
                                                Wkb, 0, 256, TD_, TD_,
                                                kb, 131072, TD_, bk, 0,
                                                inc, theta, 1.0f / TTXT, TTXT);
    // vT[d][t] = Wv[d][d'] . embT[t][d'] + bv[d]   (bias by m, no rope)
    gemm_bf<<<dim3(2, 4, bn), 256, 0, stream>>>(dflag, Wvb, 0, 256, TD_,
                                                embT, 131072, 256, TTXT, TD_,
                                                vtb, 131072, TTXT, bv, 1,
                                                inc, theta, 0.f, 0);

    attn_mfma<<<dim3(16, H_, bn), 256, 0, stream>>>(qb, kb, vtb,
                                                    tmask + (size_t)b0 * TTXT, aob);

    // Out[c][t] = (Wo[c][d] . ao[t][d] + bo[c] + x[c][t]) * lmask[t]
    gemm_bf_out<<<dim3(4, 8, bn), 256, 0, stream>>>(dflag, Wob, 0, 256, CH_,
                                                    aob, 256000, 256, TLAT, TD_,
                                                    bo, x, xoffE,
                                                    lmask, (size_t)b0 * TLAT,
                                                    d_out, xoffE, (size_t)CH_ * TLAT);
  }
}